// Round 2
// baseline (748.537 us; speedup 1.0000x reference)
//
#include <hip/hip_runtime.h>

// Problem constants
#define HW_    53568                // 248*216
#define B_     4
#define CIN_   384
#define NPOS_  (B_ * HW_)           // 214272
#define CHW_   (CIN_ * HW_)         // 20,570,112
#define NOUT_  20                   // 2 cls + 14 reg + 4 dir
#define NW_    (CIN_ * NOUT_)       // 7680 combined weights
#define NS_    6                    // K-splits
#define CSPL_  (CIN_ / NS_)         // 64 channels per split
#define TPB_   256
#define PPT_   4                    // consecutive positions per thread (float4)
#define TSPL_  (NPOS_ / PPT_)       // 53568 threads per split
#define BLKX_  ((TSPL_ + TPB_ - 1) / TPB_)  // 210
#define OUTN_  (B_ * NOUT_ * HW_)   // 4,285,440

// Combined weight matrix wcomb[c][o] (o: 0-1 cls, 2-15 reg, 16-19 dir)
__global__ void prep_weights(const float* __restrict__ w_cls,
                             const float* __restrict__ w_reg,
                             const float* __restrict__ w_dir,
                             float* __restrict__ wcomb) {
    int idx = blockIdx.x * blockDim.x + threadIdx.x;
    if (idx < NW_) {
        int c = idx / NOUT_;
        int o = idx - c * NOUT_;
        float v;
        if (o < 2)       v = w_cls[c * 2  + o];
        else if (o < 16) v = w_reg[c * 14 + (o - 2)];
        else             v = w_dir[c * 4  + (o - 16)];
        wcomb[idx] = v;
    }
}

// Pre-fill output with biases (atomics accumulate on top). float4 stores;
// all section boundaries and HW_ are divisible by 4.
__global__ __launch_bounds__(TPB_) void init_out(const float* __restrict__ b_cls,
                                                 const float* __restrict__ b_reg,
                                                 const float* __restrict__ b_dir,
                                                 float* __restrict__ out) {
    int i4 = blockIdx.x * blockDim.x + threadIdx.x;
    if (i4 >= OUTN_ / 4) return;
    int e = i4 * 4;
    float v;
    if (e < B_ * 2 * HW_) {
        v = b_cls[(e / HW_) % 2];
    } else if (e < B_ * 2 * HW_ + B_ * 14 * HW_) {
        int r = e - B_ * 2 * HW_;
        v = b_reg[(r / HW_) % 14];
    } else {
        int r = e - B_ * 2 * HW_ - B_ * 14 * HW_;
        v = b_dir[(r / HW_) % 4];
    }
    ((float4*)out)[i4] = make_float4(v, v, v, v);
}

__device__ __forceinline__ void fma4(float4& a, float w, const float4& x) {
    a.x += w * x.x; a.y += w * x.y; a.z += w * x.z; a.w += w * x.w;
}

// grid (BLKX_, NS_): blockIdx.y selects the 64-channel slice.
__global__ __launch_bounds__(TPB_) void head_split(const float* __restrict__ x,
                                                   const float* __restrict__ wcomb,
                                                   float* __restrict__ out) {
    __shared__ __align__(16) float lw[CSPL_ * NOUT_];   // 5120 B
    const int c0 = (int)blockIdx.y * CSPL_;
    for (int i = threadIdx.x; i < CSPL_ * NOUT_; i += TPB_)
        lw[i] = wcomb[c0 * NOUT_ + i];
    __syncthreads();

    int t = (int)blockIdx.x * TPB_ + (int)threadIdx.x;
    if (t >= TSPL_) return;
    int p0 = t * PPT_;                 // 4 consecutive positions, same batch
    int b  = p0 / HW_;
    int s  = p0 - b * HW_;
    const float* xp = x + (size_t)b * CHW_ + (size_t)c0 * HW_ + s;

    float4 acc[NOUT_];
#pragma unroll
    for (int o = 0; o < NOUT_; ++o) acc[o] = make_float4(0.f, 0.f, 0.f, 0.f);

#pragma unroll 4
    for (int c = 0; c < CSPL_; ++c) {
        float4 xv = *(const float4*)(xp + (size_t)c * HW_);   // 16B coalesced
        const float4* wr = (const float4*)&lw[c * NOUT_];     // broadcast reads
#pragma unroll
        for (int q = 0; q < 5; ++q) {
            float4 w = wr[q];
            fma4(acc[4 * q + 0], w.x, xv);
            fma4(acc[4 * q + 1], w.y, xv);
            fma4(acc[4 * q + 2], w.z, xv);
            fma4(acc[4 * q + 3], w.w, xv);
        }
    }

    float* out_cls = out;
    float* out_reg = out + (size_t)B_ * 2 * HW_;
    float* out_dir = out_reg + (size_t)B_ * 14 * HW_;
#pragma unroll
    for (int o = 0; o < 2; ++o) {
        const float* a = (const float*)&acc[o];
#pragma unroll
        for (int j = 0; j < PPT_; ++j)
            atomicAdd(&out_cls[(size_t)(b * 2 + o) * HW_ + s + j], a[j]);
    }
#pragma unroll
    for (int o = 0; o < 14; ++o) {
        const float* a = (const float*)&acc[2 + o];
#pragma unroll
        for (int j = 0; j < PPT_; ++j)
            atomicAdd(&out_reg[(size_t)(b * 14 + o) * HW_ + s + j], a[j]);
    }
#pragma unroll
    for (int o = 0; o < 4; ++o) {
        const float* a = (const float*)&acc[16 + o];
#pragma unroll
        for (int j = 0; j < PPT_; ++j)
            atomicAdd(&out_dir[(size_t)(b * 4 + o) * HW_ + s + j], a[j]);
    }
}

extern "C" void kernel_launch(void* const* d_in, const int* in_sizes, int n_in,
                              void* d_out, int out_size, void* d_ws, size_t ws_size,
                              hipStream_t stream) {
    const float* x     = (const float*)d_in[0];
    const float* w_cls = (const float*)d_in[1];
    const float* b_cls = (const float*)d_in[2];
    const float* w_reg = (const float*)d_in[3];
    const float* b_reg = (const float*)d_in[4];
    const float* w_dir = (const float*)d_in[5];
    const float* b_dir = (const float*)d_in[6];
    float* out   = (float*)d_out;
    float* wcomb = (float*)d_ws;    // needs 30720 B

    prep_weights<<<(NW_ + 255) / 256, 256, 0, stream>>>(w_cls, w_reg, w_dir, wcomb);
    init_out<<<(OUTN_ / 4 + TPB_ - 1) / TPB_, TPB_, 0, stream>>>(b_cls, b_reg, b_dir, out);
    head_split<<<dim3(BLKX_, NS_), TPB_, 0, stream>>>(x, wcomb, out);
}

// Round 3
// 443.952 us; speedup vs baseline: 1.6861x; 1.6861x over previous
//
#include <hip/hip_runtime.h>

// Problem constants
#define HW_    53568                // 248*216
#define B_     4
#define CIN_   384
#define NPOS_  (B_ * HW_)           // 214272 = 837 * 256 exactly
#define CHW_   (CIN_ * HW_)         // 20,570,112
#define NOUT_  20                   // 2 cls + 14 reg + 4 dir
#define NW_    (CIN_ * NOUT_)       // 7680 combined weights
#define TPB_   256
#define NBLK_  (NPOS_ / TPB_)       // 837 (exact)
#define UNR_   8                    // x-loads staged per chunk

// Combined weight matrix wcomb[c][o] (o: 0-1 cls, 2-15 reg, 16-19 dir),
// biases appended at NW_.
__global__ void prep_weights(const float* __restrict__ w_cls,
                             const float* __restrict__ b_cls,
                             const float* __restrict__ w_reg,
                             const float* __restrict__ b_reg,
                             const float* __restrict__ w_dir,
                             const float* __restrict__ b_dir,
                             float* __restrict__ wcomb) {
    int idx = blockIdx.x * blockDim.x + threadIdx.x;
    if (idx < NW_) {
        int c = idx / NOUT_;
        int o = idx - c * NOUT_;
        float v;
        if (o < 2)       v = w_cls[c * 2  + o];
        else if (o < 16) v = w_reg[c * 14 + (o - 2)];
        else             v = w_dir[c * 4  + (o - 16)];
        wcomb[idx] = v;
    } else if (idx < NW_ + NOUT_) {
        int o = idx - NW_;
        float v;
        if (o < 2)       v = b_cls[o];
        else if (o < 16) v = b_reg[o - 2];
        else             v = b_dir[o - 16];
        wcomb[idx] = v;
    }
}

// One thread per spatial position. x loads: 4 B/lane coalesced (256 B/wave).
// Weights: wave-uniform indices -> scalar loads through the constant cache.
// Accumulators: 20 floats/thread. No LDS, no atomics.
__global__ __launch_bounds__(TPB_) void head_fused(
        const float* __restrict__ x,
        const float* __restrict__ wcomb,
        float* __restrict__ out) {
    const int p = (int)blockIdx.x * TPB_ + (int)threadIdx.x;   // < NPOS_ always
    const unsigned b = (unsigned)p / HW_;
    const unsigned s = (unsigned)p - b * HW_;
    const float* xp = x + (size_t)b * CHW_ + s;

    float acc[NOUT_];
#pragma unroll
    for (int o = 0; o < NOUT_; ++o) acc[o] = wcomb[NW_ + o];   // bias (scalar load)

    // Hot loop: stage UNR_ coalesced x loads, then 20 FMAs each with
    // SGPR-resident weights.
    for (int cc = 0; cc < CIN_; cc += UNR_) {
        float xv[UNR_];
#pragma unroll
        for (int u = 0; u < UNR_; ++u)
            xv[u] = xp[(size_t)(cc + u) * HW_];
#pragma unroll
        for (int u = 0; u < UNR_; ++u) {
            const float* w = &wcomb[(cc + u) * NOUT_];         // uniform -> s_load
#pragma unroll
            for (int o = 0; o < NOUT_; ++o)
                acc[o] += w[o] * xv[u];
        }
    }

    float* out_cls = out;
    float* out_reg = out + (size_t)B_ * 2 * HW_;
    float* out_dir = out_reg + (size_t)B_ * 14 * HW_;
#pragma unroll
    for (int o = 0; o < 2; ++o)
        out_cls[(size_t)(b * 2 + o) * HW_ + s] = acc[o];
#pragma unroll
    for (int o = 0; o < 14; ++o)
        out_reg[(size_t)(b * 14 + o) * HW_ + s] = acc[2 + o];
#pragma unroll
    for (int o = 0; o < 4; ++o)
        out_dir[(size_t)(b * 4 + o) * HW_ + s] = acc[16 + o];
}

extern "C" void kernel_launch(void* const* d_in, const int* in_sizes, int n_in,
                              void* d_out, int out_size, void* d_ws, size_t ws_size,
                              hipStream_t stream) {
    const float* x     = (const float*)d_in[0];
    const float* w_cls = (const float*)d_in[1];
    const float* b_cls = (const float*)d_in[2];
    const float* w_reg = (const float*)d_in[3];
    const float* b_reg = (const float*)d_in[4];
    const float* w_dir = (const float*)d_in[5];
    const float* b_dir = (const float*)d_in[6];
    float* out   = (float*)d_out;
    float* wcomb = (float*)d_ws;    // needs 30800 B

    prep_weights<<<(NW_ + NOUT_ + 255) / 256, 256, 0, stream>>>(
        w_cls, b_cls, w_reg, b_reg, w_dir, b_dir, wcomb);
    head_fused<<<NBLK_, TPB_, 0, stream>>>(x, wcomb, out);
}